// Round 1
// baseline (198.007 us; speedup 1.0000x reference)
//
#include <hip/hip_runtime.h>

// Problem constants
#define D 256
#define S 128
#define B 32
#define ROWS 16   // rows per block in k1
#define DC 32     // d-chunk per block in k2

// K1: Xl[r,d] = sum_k emb[X[r],k] * Wl[d,k] + bl[d]   (and same for Xr)
// Block: 16 rows x 256 d. A-row loads are block-uniform (L1 broadcast);
// W loads are per-thread float4 streams along k (L2-cached, W = 256 KB each).
__global__ __launch_bounds__(256) void k1_gemm(
    const int* __restrict__ X, const float* __restrict__ emb,
    const float* __restrict__ Wl, const float* __restrict__ bl,
    const float* __restrict__ Wr, const float* __restrict__ br,
    float* __restrict__ Xl, float* __restrict__ Xr)
{
    const int d = threadIdx.x;
    const int rowBase = blockIdx.x * ROWS;

    const float4* __restrict__ a4[ROWS];
#pragma unroll
    for (int r = 0; r < ROWS; ++r) {
        const int tok = X[rowBase + r];           // block-uniform -> s_load
        a4[r] = (const float4*)(emb + (size_t)tok * D);
    }
    const float4* __restrict__ wl4 = (const float4*)(Wl + (size_t)d * D);
    const float4* __restrict__ wr4 = (const float4*)(Wr + (size_t)d * D);

    float accl[ROWS], accr[ROWS];
#pragma unroll
    for (int r = 0; r < ROWS; ++r) { accl[r] = 0.f; accr[r] = 0.f; }

    for (int ks = 0; ks < D / 4; ++ks) {
        const float4 wl = wl4[ks];
        const float4 wr = wr4[ks];
#pragma unroll
        for (int r = 0; r < ROWS; ++r) {
            const float4 x = a4[r][ks];           // wave-uniform address
            accl[r] += x.x * wl.x + x.y * wl.y + x.z * wl.z + x.w * wl.w;
            accr[r] += x.x * wr.x + x.y * wr.y + x.z * wr.z + x.w * wr.w;
        }
    }
    const float bld = bl[d], brd = br[d];
#pragma unroll
    for (int r = 0; r < ROWS; ++r) {
        Xl[(size_t)(rowBase + r) * D + d] = accl[r] + bld;
        Xr[(size_t)(rowBase + r) * D + d] = accr[r] + brd;
    }
}

// K2: pooled[b,d] = sum_{i,j} relu(Xl[b,j,d] + Xr[b,i,d])
//                 = 0.5 * ( S*(sum_j Xl + sum_i Xr) + sum_{ij} |Xl_j + Xr_i| )
// Block: one (b, 32-d chunk). 8 threads per d, each covering 16 i values.
// Inner loop: 1 LDS broadcast read + 8x (v_add + v_add-with-abs) = 2 ops/position.
__global__ __launch_bounds__(256) void k2_pairsum(
    const float* __restrict__ Xl, const float* __restrict__ Xr,
    float* __restrict__ pooled)
{
    __shared__ float lxl[S * DC];   // [j][dl]
    __shared__ float lxr[S * DC];   // [i][dl]
    __shared__ float red[256];

    const int b   = blockIdx.x >> 3;   // 0..31
    const int dc  = blockIdx.x & 7;    // 0..7 (chunk of 32 d's)
    const int tid = threadIdx.x;
    const int dl  = tid & (DC - 1);
    const int igrp = tid >> 5;         // 0..7

    const size_t base = (size_t)b * S * D + (size_t)dc * DC;
    for (int e = tid; e < S * DC; e += 256) {
        const int j = e >> 5, d2 = e & (DC - 1);
        lxl[e] = Xl[base + (size_t)j * D + d2];
        lxr[e] = Xr[base + (size_t)j * D + d2];
    }
    __syncthreads();

    float sum_abs = 0.f;
#pragma unroll
    for (int ig = 0; ig < 2; ++ig) {
        float xr[8];
#pragma unroll
        for (int u = 0; u < 8; ++u)
            xr[u] = lxr[(igrp * 16 + ig * 8 + u) * DC + dl];
        for (int j = 0; j < S; ++j) {
            const float x = lxl[j * DC + dl];
#pragma unroll
            for (int u = 0; u < 8; ++u)
                sum_abs += fabsf(x + xr[u]);
        }
    }
    red[tid] = sum_abs;
    __syncthreads();

    if (igrp == 0) {            // tid < 32, dl == tid
        float tot = 0.f;
#pragma unroll
        for (int g = 0; g < 8; ++g) tot += red[g * 32 + dl];
        float sl = 0.f, sr = 0.f;
        for (int j = 0; j < S; ++j) {
            sl += lxl[j * DC + dl];
            sr += lxr[j * DC + dl];
        }
        pooled[(size_t)b * D + (size_t)dc * DC + dl] =
            0.5f * ((float)S * (sl + sr) + tot);
    }
}

// K3: out[b,d] = sum_k pooled[b,k] * Wrn[d,k] + S*S * brn[d]
__global__ __launch_bounds__(256) void k3_out(
    const float* __restrict__ pooled, const float* __restrict__ Wrn,
    const float* __restrict__ brn, float* __restrict__ out)
{
    __shared__ float lp[D];
    const int b = blockIdx.x;
    const int d = threadIdx.x;
    lp[d] = pooled[(size_t)b * D + d];
    __syncthreads();

    const float4* __restrict__ w4 = (const float4*)(Wrn + (size_t)d * D);
    const float4* __restrict__ p4 = (const float4*)lp;
    float acc = 0.f;
#pragma unroll 4
    for (int ks = 0; ks < D / 4; ++ks) {
        const float4 w = w4[ks];
        const float4 p = p4[ks];
        acc += p.x * w.x + p.y * w.y + p.z * w.z + p.w * w.w;
    }
    out[(size_t)b * D + d] = acc + (float)(S * S) * brn[d];
}

extern "C" void kernel_launch(void* const* d_in, const int* in_sizes, int n_in,
                              void* d_out, int out_size, void* d_ws, size_t ws_size,
                              hipStream_t stream) {
    const int*   X   = (const int*)d_in[0];
    const float* emb = (const float*)d_in[1];
    const float* Wl  = (const float*)d_in[2];
    const float* bl  = (const float*)d_in[3];
    const float* Wr  = (const float*)d_in[4];
    const float* br  = (const float*)d_in[5];
    const float* Wrn = (const float*)d_in[6];
    const float* brn = (const float*)d_in[7];
    float* out = (float*)d_out;

    float* ws     = (float*)d_ws;
    float* Xl     = ws;                         // 4096*256
    float* Xr     = ws + (size_t)B * S * D;     // 4096*256
    float* pooled = ws + 2 * (size_t)B * S * D; // 32*256

    k1_gemm<<<(B * S) / ROWS, 256, 0, stream>>>(X, emb, Wl, bl, Wr, br, Xl, Xr);
    k2_pairsum<<<B * (D / DC), 256, 0, stream>>>(Xl, Xr, pooled);
    k3_out<<<B, 256, 0, stream>>>(pooled, Wrn, brn, out);
}

// Round 2
// 135.605 us; speedup vs baseline: 1.4602x; 1.4602x over previous
//
#include <hip/hip_runtime.h>

#define D 256
#define S 128
#define B 32
#define RT 8      // rows per block in k1
#define DC 16     // d-chunk per block in k2

__device__ __forceinline__ float dot4(float4 a, float4 b) {
    return a.x * b.x + a.y * b.y + a.z * b.z + a.w * b.w;
}

// K1: Xl[r,d] = sum_k emb[X[r],k]*Wl[d,k] + bl[d]  (and Xr with Wr,br)
// Block: 8 rows x 256 d. A rows staged in LDS (8 KB) with coalesced float4
// loads; inner loop: 2 per-lane W float4 streams (L1/L2) + 8 broadcast
// ds_read_b128 + 64 FMA. Grid 512 -> 2 blocks/CU, 8 waves/CU.
__global__ __launch_bounds__(256) void k1_gemm(
    const int* __restrict__ X, const float* __restrict__ emb,
    const float* __restrict__ Wl, const float* __restrict__ bl,
    const float* __restrict__ Wr, const float* __restrict__ br,
    float* __restrict__ Xl, float* __restrict__ Xr)
{
    __shared__ float4 As[RT][D / 4];   // 8 rows x 64 float4 = 8 KB

    const int tid = threadIdx.x;
    const int rowBase = blockIdx.x * RT;

    // stage A: 512 float4, 2 per thread, coalesced within each row
    {
        const int f0 = tid;           // f = r*64 + kf
        const int f1 = tid + 256;
        const int r0 = f0 >> 6, kf0 = f0 & 63;
        const int r1 = f1 >> 6, kf1 = f1 & 63;
        const int tok0 = X[rowBase + r0];
        const int tok1 = X[rowBase + r1];
        As[r0][kf0] = ((const float4*)(emb + (size_t)tok0 * D))[kf0];
        As[r1][kf1] = ((const float4*)(emb + (size_t)tok1 * D))[kf1];
    }
    __syncthreads();

    const int d = tid;
    const float4* __restrict__ wl4 = (const float4*)(Wl + (size_t)d * D);
    const float4* __restrict__ wr4 = (const float4*)(Wr + (size_t)d * D);

    float accl[RT], accr[RT];
#pragma unroll
    for (int r = 0; r < RT; ++r) { accl[r] = 0.f; accr[r] = 0.f; }

#pragma unroll 4
    for (int kk = 0; kk < D / 4; ++kk) {
        const float4 wlv = wl4[kk];
        const float4 wrv = wr4[kk];
#pragma unroll
        for (int r = 0; r < RT; ++r) {
            const float4 a = As[r][kk];   // broadcast ds_read_b128
            accl[r] += dot4(a, wlv);
            accr[r] += dot4(a, wrv);
        }
    }
    const float bld = bl[d], brd = br[d];
#pragma unroll
    for (int r = 0; r < RT; ++r) {
        Xl[(size_t)(rowBase + r) * D + d] = accl[r] + bld;
        Xr[(size_t)(rowBase + r) * D + d] = accr[r] + brd;
    }
}

// K2: pooled[b,d] = 0.5*( S*(sum_j xl + sum_i xr) + sum_{ij}|xl_j + xr_i| )
// Block: (b, 16-d chunk). 16 threads per d x 16 i-groups of 8.
// Linear terms folded into the main loop; no serial tail.
__global__ __launch_bounds__(256) void k2_pairsum(
    const float* __restrict__ Xl, const float* __restrict__ Xr,
    float* __restrict__ pooled)
{
    __shared__ float lxl[S * DC];   // [j][dl] : 8 KB
    __shared__ float lxr[S * DC];
    __shared__ float red[256];

    const int b   = blockIdx.x >> 4;   // 0..31
    const int dc  = blockIdx.x & 15;   // 0..15
    const int tid = threadIdx.x;
    const int dl  = tid & (DC - 1);
    const int ig  = tid >> 4;          // 0..15, 8 i's each

    const size_t base = (size_t)b * S * D + (size_t)dc * DC;
    // stage as float4: 512 per array, 2 per thread
    {
        float4* lxl4 = (float4*)lxl;
        float4* lxr4 = (float4*)lxr;
#pragma unroll
        for (int t = 0; t < 2; ++t) {
            const int e4 = tid + t * 256;       // e4 = j*4 + df
            const int j = e4 >> 2, df = e4 & 3;
            const float4* pl = (const float4*)(Xl + base + (size_t)j * D);
            const float4* pr = (const float4*)(Xr + base + (size_t)j * D);
            lxl4[e4] = pl[df];
            lxr4[e4] = pr[df];
        }
    }
    __syncthreads();

    float xr[8];
    float sr = 0.f;
#pragma unroll
    for (int u = 0; u < 8; ++u) {
        xr[u] = lxr[(ig * 8 + u) * DC + dl];
        sr += xr[u];
    }

    float sabs = 0.f, sxl = 0.f;
#pragma unroll 4
    for (int j = 0; j < S; ++j) {
        const float x = lxl[j * DC + dl];   // broadcast within 4-lane groups
        sxl += x;
#pragma unroll
        for (int u = 0; u < 8; ++u)
            sabs += fabsf(x + xr[u]);
    }

    red[tid] = sabs + (float)S * sr;
    __syncthreads();

    if (tid < DC) {   // dl == tid, ig == 0, has its own sxl
        float tot = 0.f;
#pragma unroll
        for (int g = 0; g < 16; ++g) tot += red[g * DC + tid];
        pooled[(size_t)b * D + (size_t)dc * DC + tid] =
            0.5f * ((float)S * sxl + tot);
    }
}

// K3: out[b,d] = sum_k pooled[b,k]*Wrn[d,k] + S*S*brn[d]
// Block: (b, 32-d chunk); 8 threads per output over k, LDS reduce.
__global__ __launch_bounds__(256) void k3_out(
    const float* __restrict__ pooled, const float* __restrict__ Wrn,
    const float* __restrict__ brn, float* __restrict__ out)
{
    __shared__ float lp[D];
    __shared__ float red[256];
    const int bb = blockIdx.x >> 3;   // 0..31
    const int dc = blockIdx.x & 7;    // 0..7 (32 d's each)
    const int tid = threadIdx.x;
    lp[tid] = pooled[(size_t)bb * D + tid];
    __syncthreads();

    const int dl = tid & 31;
    const int kg = tid >> 5;          // 0..7, 8 float4 each
    const int d = dc * 32 + dl;
    const float4* __restrict__ w4 = (const float4*)(Wrn + (size_t)d * D) + kg * 8;
    const float4* __restrict__ p4 = (const float4*)lp + kg * 8;
    float acc = 0.f;
#pragma unroll
    for (int f = 0; f < 8; ++f) acc += dot4(w4[f], p4[f]);

    red[tid] = acc;
    __syncthreads();
    if (tid < 32) {
        float s = 0.f;
#pragma unroll
        for (int g = 0; g < 8; ++g) s += red[g * 32 + tid];
        out[(size_t)bb * D + dc * 32 + tid] = s + (float)(S * S) * brn[dc * 32 + tid];
    }
}

extern "C" void kernel_launch(void* const* d_in, const int* in_sizes, int n_in,
                              void* d_out, int out_size, void* d_ws, size_t ws_size,
                              hipStream_t stream) {
    const int*   X   = (const int*)d_in[0];
    const float* emb = (const float*)d_in[1];
    const float* Wl  = (const float*)d_in[2];
    const float* bl  = (const float*)d_in[3];
    const float* Wr  = (const float*)d_in[4];
    const float* br  = (const float*)d_in[5];
    const float* Wrn = (const float*)d_in[6];
    const float* brn = (const float*)d_in[7];
    float* out = (float*)d_out;

    float* ws     = (float*)d_ws;
    float* Xl     = ws;                         // 1M floats
    float* Xr     = ws + (size_t)B * S * D;     // 1M floats
    float* pooled = ws + 2 * (size_t)B * S * D; // 8192 floats

    k1_gemm<<<(B * S) / RT, 256, 0, stream>>>(X, emb, Wl, bl, Wr, br, Xl, Xr);
    k2_pairsum<<<B * (D / DC), 256, 0, stream>>>(Xl, Xr, pooled);
    k3_out<<<B * 8, 256, 0, stream>>>(pooled, Wrn, brn, out);
}